// Round 12
// baseline (332.375 us; speedup 1.0000x reference)
//
#include <hip/hip_runtime.h>
#include <hip/hip_bf16.h>
#include <math.h>

// Problem constants
#define Bn 4
#define Tn 1024
#define Cn 1024
#define Hn 16
#define Kn 64
#define DFn 2048
#define NCn 16      // WKV chunks
#define Ln 64       // chunk length (NCn*Ln == Tn)

typedef __bf16 bf16x8 __attribute__((ext_vector_type(8)));
typedef float f32x4 __attribute__((ext_vector_type(4)));

#define GLD(dst, src) \
  __builtin_amdgcn_global_load_lds((__attribute__((address_space(1))) const void*)(src), \
                                   (__attribute__((address_space(3))) void*)(dst), 16, 0, 0)

__device__ __forceinline__ float rdlane(float v, int l) {
  return __int_as_float(__builtin_amdgcn_readlane(__float_as_int(v), l));
}

__device__ __forceinline__ unsigned short bfbits(float f) {
  union { __hip_bfloat16 h; unsigned short u; } cv;
  cv.h = __float2bfloat16(f);
  return cv.u;
}

// ---------------------------------------------------------------------------
// Combined setup kernel: blocks [0, 11456) convert+transpose all weights to
// bf16 B^T layout; blocks [11456, 15552) do the prep elementwise pass.
// ---------------------------------------------------------------------------
__global__ __launch_bounds__(256) void k_setup(const float* __restrict__ w1,
                                               const float* __restrict__ w2,
                                               const float* __restrict__ Wr,
                                               const float* __restrict__ Wk,
                                               const float* __restrict__ Wvg,
                                               const float* __restrict__ Wo,
                                               const float* __restrict__ x,
                                               const float* __restrict__ maa_x,
                                               __hip_bfloat16* __restrict__ w1t,
                                               __hip_bfloat16* __restrict__ w2t,
                                               __hip_bfloat16* __restrict__ Wrt,
                                               __hip_bfloat16* __restrict__ Wkt,
                                               __hip_bfloat16* __restrict__ Wvgt,
                                               __hip_bfloat16* __restrict__ Wot,
                                               float* __restrict__ xx,
                                               __hip_bfloat16* __restrict__ xxx16) {
  int b = blockIdx.x;
  if (b >= 11456) {
    int idx = (b - 11456) * 256 + threadIdx.x;
    int c4 = idx & 255;
    int bt = idx >> 8;
    int t = bt & (Tn - 1);
    const float4* x4 = (const float4*)x;
    float4 xv = x4[idx];
    float4 xp;
    if (t > 0) xp = x4[idx - 256];
    else { xp.x = 0.f; xp.y = 0.f; xp.z = 0.f; xp.w = 0.f; }
    float4 d;
    d.x = xp.x - xv.x; d.y = xp.y - xv.y; d.z = xp.z - xv.z; d.w = xp.w - xv.w;
    float4 m = ((const float4*)maa_x)[c4];
    ushort4 o;
    o.x = bfbits(fmaf(d.x, m.x, xv.x));
    o.y = bfbits(fmaf(d.y, m.y, xv.y));
    o.z = bfbits(fmaf(d.z, m.z, xv.z));
    o.w = bfbits(fmaf(d.w, m.w, xv.w));
    ((float4*)xx)[idx] = d;
    ((ushort4*)xxx16)[idx] = o;
    return;
  }
  const float* W; __hip_bfloat16* Wt; int K, N, nx, rel;
  if (b < 96)        { W = w1;  Wt = w1t;  K = 1024; N = 96;   nx = 3;   rel = b; }
  else if (b < 192)  { int l = (b - 96) >> 5; rel = (b - 96) & 31;
                       W = w2 + l * 32768; Wt = w2t + l * 32768; K = 32; N = 1024; nx = 32; }
  else if (b < 1216) { W = Wr;  Wt = Wrt;  K = 1024; N = 1024; nx = 32;  rel = b - 192; }
  else if (b < 2240) { W = Wk;  Wt = Wkt;  K = 1024; N = 1024; nx = 32;  rel = b - 1216; }
  else if (b < 8384) { W = Wvg; Wt = Wvgt; K = 1024; N = 6144; nx = 192; rel = b - 2240; }
  else               { W = Wo;  Wt = Wot;  K = 3072; N = 1024; nx = 32;  rel = b - 8384; }
  int n0 = (rel % nx) * 32, k0 = (rel / nx) * 32;
  __shared__ float tile[32][33];
  int tid = threadIdx.x;
  int c = tid & 31, r = tid >> 5;   // r = 0..7
  #pragma unroll
  for (int i = 0; i < 4; ++i)
    tile[r + i * 8][c] = W[(size_t)(k0 + r + i * 8) * N + n0 + c];
  __syncthreads();
  #pragma unroll
  for (int i = 0; i < 4; ++i)
    Wt[(size_t)(n0 + r + i * 8) * K + k0 + c] = __float2bfloat16(tile[c][r + i * 8]);
}

// ---------------------------------------------------------------------------
// Kernel 2 (MFMA): m1 = tanh(xxx16 @ w1t^T)  -> bf16 (4096 x 96)
// ---------------------------------------------------------------------------
__global__ __launch_bounds__(256) void k_mix1_16(const __hip_bfloat16* __restrict__ A,
                                                 const __hip_bfloat16* __restrict__ Bt,
                                                 __hip_bfloat16* __restrict__ m1) {
  const int K = 1024;
  __shared__ __align__(16) __hip_bfloat16 Al[128 * 32];
  __shared__ __align__(16) __hip_bfloat16 Bl[96 * 32];
  const int tid = threadIdx.x;
  const int wid = tid >> 6, lane = tid & 63;
  const int wr = wid >> 1, wc = wid & 1;
  const int row0 = blockIdx.x * 128;
  const char* gsrc[4];
  char* ldst[4];
  bool act[4];
  #pragma unroll
  for (int i = 0; i < 4; ++i) {
    const int s = i * 4 + wid;
    act[i] = (s < 14);
    const int ss = act[i] ? s : 0;
    if (ss < 8) {
      const int r = ss * 16 + (lane >> 2);
      gsrc[i] = (const char*)(A + (size_t)(row0 + r) * K) + (lane & 3) * 16;
      ldst[i] = (char*)&Al[0] + ss * 1024;
    } else {
      const int r = (ss - 8) * 16 + (lane >> 2);
      gsrc[i] = (const char*)(Bt + (size_t)r * K) + (lane & 3) * 16;
      ldst[i] = (char*)&Bl[0] + (ss - 8) * 1024;
    }
  }
  f32x4 acc[4][3];
  #pragma unroll
  for (int i = 0; i < 4; ++i)
    #pragma unroll
    for (int j = 0; j < 3; ++j)
      acc[i][j] = (f32x4){0.f, 0.f, 0.f, 0.f};
  const int g = lane >> 4, m = lane & 15;
  for (int k0 = 0; k0 < K; k0 += 32) {
    #pragma unroll
    for (int i = 0; i < 4; ++i) if (act[i]) GLD(ldst[i], gsrc[i]);
    #pragma unroll
    for (int i = 0; i < 4; ++i) gsrc[i] += 64;
    __syncthreads();
    bf16x8 af[4], bfr[3];
    #pragma unroll
    for (int i = 0; i < 4; ++i)
      af[i] = *(const bf16x8*)&Al[(wr * 64 + i * 16 + m) * 32 + g * 8];
    #pragma unroll
    for (int j = 0; j < 3; ++j)
      bfr[j] = *(const bf16x8*)&Bl[(wc * 48 + j * 16 + m) * 32 + g * 8];
    #pragma unroll
    for (int i = 0; i < 4; ++i)
      #pragma unroll
      for (int j = 0; j < 3; ++j)
        acc[i][j] = __builtin_amdgcn_mfma_f32_16x16x32_bf16(af[i], bfr[j], acc[i][j], 0, 0, 0);
    __syncthreads();
  }
  #pragma unroll
  for (int i = 0; i < 4; ++i) {
    const int grow = row0 + wr * 64 + i * 16 + g * 4;
    #pragma unroll
    for (int j = 0; j < 3; ++j) {
      const int gcol = wc * 48 + j * 16 + m;
      #pragma unroll
      for (int e = 0; e < 4; ++e)
        m1[(size_t)(grow + e) * 96 + gcol] = __float2bfloat16(tanhf(acc[i][j][e]));
    }
  }
}

// ---------------------------------------------------------------------------
// Kernel 3 (MFMA, one-shot K): m_l = m1 @ w2t[l]^T (K=32 each), fused epilogue
// ---------------------------------------------------------------------------
__global__ __launch_bounds__(256) void k_mix2_16(const __hip_bfloat16* __restrict__ m1,
                                                 const __hip_bfloat16* __restrict__ w2t,
                                                 const float* __restrict__ x,
                                                 const float* __restrict__ xx,
                                                 const float* __restrict__ maa_k,
                                                 const float* __restrict__ maa_v,
                                                 const float* __restrict__ maa_r,
                                                 __hip_bfloat16* __restrict__ xk,
                                                 __hip_bfloat16* __restrict__ xv,
                                                 __hip_bfloat16* __restrict__ xr) {
  __shared__ __align__(16) __hip_bfloat16 Al[128 * 96];     // 24 KB contiguous
  __shared__ __align__(16) __hip_bfloat16 Bl[3 * 64 * 32];  // 12 KB
  const int tid = threadIdx.x;
  const int wid = tid >> 6, lane = tid & 63;
  const int wr = wid >> 1, wc = wid & 1;
  const int row0 = blockIdx.y * 128, col0 = blockIdx.x * 64;
  {
    const char* abase = (const char*)(m1 + (size_t)row0 * 96) + lane * 16;
    #pragma unroll
    for (int i = 0; i < 6; ++i) {
      const int s = wid + i * 4;          // 0..23
      GLD((char*)&Al[0] + s * 1024, abase + s * 1024);
    }
  }
  {
    const char* bbase = (const char*)w2t + (size_t)col0 * 64 + lane * 16;
    #pragma unroll
    for (int i = 0; i < 3; ++i) {
      const int s = wid + i * 4;          // 0..11
      const int l = s >> 2, q = s & 3;
      GLD((char*)&Bl[0] + s * 1024, bbase + (size_t)l * 65536 + q * 1024);
    }
  }
  __syncthreads();
  const int g = lane >> 4, m = lane & 15;
  f32x4 a0[4][2], a1[4][2], a2[4][2];
  #pragma unroll
  for (int i = 0; i < 4; ++i)
    #pragma unroll
    for (int j = 0; j < 2; ++j) {
      a0[i][j] = (f32x4){0.f,0.f,0.f,0.f};
      a1[i][j] = (f32x4){0.f,0.f,0.f,0.f};
      a2[i][j] = (f32x4){0.f,0.f,0.f,0.f};
    }
  #pragma unroll
  for (int l = 0; l < 3; ++l) {
    bf16x8 af[4], bfj[2];
    #pragma unroll
    for (int i = 0; i < 4; ++i)
      af[i] = *(const bf16x8*)&Al[(wr * 64 + i * 16 + m) * 96 + l * 32 + g * 8];
    #pragma unroll
    for (int j = 0; j < 2; ++j)
      bfj[j] = *(const bf16x8*)&Bl[(l * 64 + wc * 32 + j * 16 + m) * 32 + g * 8];
    #pragma unroll
    for (int i = 0; i < 4; ++i)
      #pragma unroll
      for (int j = 0; j < 2; ++j) {
        if (l == 0) a0[i][j] = __builtin_amdgcn_mfma_f32_16x16x32_bf16(af[i], bfj[j], a0[i][j], 0, 0, 0);
        if (l == 1) a1[i][j] = __builtin_amdgcn_mfma_f32_16x16x32_bf16(af[i], bfj[j], a1[i][j], 0, 0, 0);
        if (l == 2) a2[i][j] = __builtin_amdgcn_mfma_f32_16x16x32_bf16(af[i], bfj[j], a2[i][j], 0, 0, 0);
      }
  }
  #pragma unroll
  for (int i = 0; i < 4; ++i) {
    const int grow = row0 + wr * 64 + i * 16 + g * 4;
    #pragma unroll
    for (int j = 0; j < 2; ++j) {
      const int gcol = col0 + wc * 32 + j * 16 + m;
      const float mk_ = maa_k[gcol], mv_ = maa_v[gcol], mr_ = maa_r[gcol];
      #pragma unroll
      for (int e = 0; e < 4; ++e) {
        const size_t off = (size_t)(grow + e) * 1024 + gcol;
        const float xval = x[off], xxv = xx[off];
        xk[off] = __float2bfloat16(fmaf(xxv, mk_ + a0[i][j][e], xval));
        xv[off] = __float2bfloat16(fmaf(xxv, mv_ + a1[i][j][e], xval));
        xr[off] = __float2bfloat16(fmaf(xxv, mr_ + a2[i][j][e], xval));
      }
    }
  }
}

// ---------------------------------------------------------------------------
// Merged r/e GEMM, BK=64: z=0: rr = xr @ Wr ; z=1: ee = exp(-exp(xk @ Wk))
// LDS 24 KB: A 128x64, B 64x64. 24 staging subtiles (8 rows x 128B each),
// 6 GLD/wave per K-step; 32 MFMA per K-step (two K=32 sub-rounds).
// ---------------------------------------------------------------------------
__global__ __launch_bounds__(256) void k_gemm_re(const __hip_bfloat16* __restrict__ Ar,
                                                 const __hip_bfloat16* __restrict__ Btr,
                                                 float* __restrict__ Cr,
                                                 const __hip_bfloat16* __restrict__ Ak,
                                                 const __hip_bfloat16* __restrict__ Btk,
                                                 float* __restrict__ Ck) {
  const int K = 1024, N = 1024;
  const int z = blockIdx.z;
  const __hip_bfloat16* A  = z ? Ak : Ar;
  const __hip_bfloat16* Bt = z ? Btk : Btr;
  float* C = z ? Ck : Cr;
  __shared__ __align__(16) __hip_bfloat16 Al[128 * 64];
  __shared__ __align__(16) __hip_bfloat16 Bl[64 * 64];
  const int tid = threadIdx.x;
  const int wid = tid >> 6, lane = tid & 63;
  const int wr = wid >> 1, wc = wid & 1;
  const int row0 = blockIdx.y * 128, col0 = blockIdx.x * 64;
  const char* gsrc[6];
  char* ldst[6];
  #pragma unroll
  for (int i = 0; i < 6; ++i) {
    const int s = wid + i * 4;            // 0..23
    if (s < 16) {
      const int r = s * 8 + (lane >> 3);
      gsrc[i] = (const char*)(A + (size_t)(row0 + r) * K) + (lane & 7) * 16;
      ldst[i] = (char*)&Al[0] + s * 1024;
    } else {
      const int r = (s - 16) * 8 + (lane >> 3);
      gsrc[i] = (const char*)(Bt + (size_t)(col0 + r) * K) + (lane & 7) * 16;
      ldst[i] = (char*)&Bl[0] + (s - 16) * 1024;
    }
  }
  f32x4 acc[4][2];
  #pragma unroll
  for (int i = 0; i < 4; ++i)
    #pragma unroll
    for (int j = 0; j < 2; ++j)
      acc[i][j] = (f32x4){0.f, 0.f, 0.f, 0.f};
  const int g = lane >> 4, m = lane & 15;
  for (int k0 = 0; k0 < K; k0 += 64) {
    #pragma unroll
    for (int i = 0; i < 6; ++i) GLD(ldst[i], gsrc[i]);
    #pragma unroll
    for (int i = 0; i < 6; ++i) gsrc[i] += 128;
    __syncthreads();
    #pragma unroll
    for (int h = 0; h < 2; ++h) {
      bf16x8 af[4], bfr[2];
      #pragma unroll
      for (int i = 0; i < 4; ++i)
        af[i] = *(const bf16x8*)&Al[(wr * 64 + i * 16 + m) * 64 + h * 32 + g * 8];
      #pragma unroll
      for (int j = 0; j < 2; ++j)
        bfr[j] = *(const bf16x8*)&Bl[(wc * 32 + j * 16 + m) * 64 + h * 32 + g * 8];
      #pragma unroll
      for (int i = 0; i < 4; ++i)
        #pragma unroll
        for (int j = 0; j < 2; ++j)
          acc[i][j] = __builtin_amdgcn_mfma_f32_16x16x32_bf16(af[i], bfr[j], acc[i][j], 0, 0, 0);
    }
    __syncthreads();
  }
  #pragma unroll
  for (int i = 0; i < 4; ++i) {
    const int grow = row0 + wr * 64 + i * 16 + g * 4;
    #pragma unroll
    for (int j = 0; j < 2; ++j) {
      const int gcol = col0 + wc * 32 + j * 16 + m;
      #pragma unroll
      for (int e = 0; e < 4; ++e) {
        float val = acc[i][j][e];
        if (z) val = expf(-expf(val));
        C[(size_t)(grow + e) * N + gcol] = val;
      }
    }
  }
}

// ---------------------------------------------------------------------------
// Fused Wvg GEMM, BK=64: LDS 32 KB (A 128x64 + B1 64x64 + B2 64x64).
// 32 staging subtiles, 8 GLD/wave per K-step; 64 MFMA per K-step.
// ---------------------------------------------------------------------------
__global__ __launch_bounds__(256) void k_gemm_vg16(const __hip_bfloat16* __restrict__ A,
                                                   const __hip_bfloat16* __restrict__ Bt,
                                                   float* __restrict__ v,
                                                   __hip_bfloat16* __restrict__ ffn) {
  const int K = 1024;
  __shared__ __align__(16) __hip_bfloat16 Al[128 * 64];
  __shared__ __align__(16) __hip_bfloat16 B1l[64 * 64];
  __shared__ __align__(16) __hip_bfloat16 B2l[64 * 64];
  const int tid = threadIdx.x;
  const int wid = tid >> 6, lane = tid & 63;
  const int wr = wid >> 1, wc = wid & 1;
  const int row0 = blockIdx.y * 128, col0 = blockIdx.x * 64;
  const char* gsrc[8];
  char* ldst[8];
  #pragma unroll
  for (int i = 0; i < 8; ++i) {
    const int s = wid + i * 4;            // 0..31
    if (s < 16) {
      const int r = s * 8 + (lane >> 3);
      gsrc[i] = (const char*)(A + (size_t)(row0 + r) * K) + (lane & 7) * 16;
      ldst[i] = (char*)&Al[0] + s * 1024;
    } else if (s < 24) {
      const int r = col0 + (s - 16) * 8 + (lane >> 3);
      gsrc[i] = (const char*)(Bt + (size_t)r * K) + (lane & 7) * 16;
      ldst[i] = (char*)&B1l[0] + (s - 16) * 1024;
    } else {
      const int r = 3072 + col0 + (s - 24) * 8 + (lane >> 3);
      gsrc[i] = (const char*)(Bt + (size_t)r * K) + (lane & 7) * 16;
      ldst[i] = (char*)&B2l[0] + (s - 24) * 1024;
    }
  }
  f32x4 a1[4][2], a2[4][2];
  #pragma unroll
  for (int i = 0; i < 4; ++i)
    #pragma unroll
    for (int j = 0; j < 2; ++j) {
      a1[i][j] = (f32x4){0.f, 0.f, 0.f, 0.f};
      a2[i][j] = (f32x4){0.f, 0.f, 0.f, 0.f};
    }
  const int g = lane >> 4, m = lane & 15;
  for (int k0 = 0; k0 < K; k0 += 64) {
    #pragma unroll
    for (int i = 0; i < 8; ++i) GLD(ldst[i], gsrc[i]);
    #pragma unroll
    for (int i = 0; i < 8; ++i) gsrc[i] += 128;
    __syncthreads();
    #pragma unroll
    for (int h = 0; h < 2; ++h) {
      bf16x8 af[4], b1f[2], b2f[2];
      #pragma unroll
      for (int i = 0; i < 4; ++i)
        af[i] = *(const bf16x8*)&Al[(wr * 64 + i * 16 + m) * 64 + h * 32 + g * 8];
      #pragma unroll
      for (int j = 0; j < 2; ++j) {
        b1f[j] = *(const bf16x8*)&B1l[(wc * 32 + j * 16 + m) * 64 + h * 32 + g * 8];
        b2f[j] = *(const bf16x8*)&B2l[(wc * 32 + j * 16 + m) * 64 + h * 32 + g * 8];
      }
      #pragma unroll
      for (int i = 0; i < 4; ++i)
        #pragma unroll
        for (int j = 0; j < 2; ++j) {
          a1[i][j] = __builtin_amdgcn_mfma_f32_16x16x32_bf16(af[i], b1f[j], a1[i][j], 0, 0, 0);
          a2[i][j] = __builtin_amdgcn_mfma_f32_16x16x32_bf16(af[i], b2f[j], a2[i][j], 0, 0, 0);
        }
    }
    __syncthreads();
  }
  const bool to_v = (col0 < 1024);
  #pragma unroll
  for (int i = 0; i < 4; ++i) {
    const int grow = row0 + wr * 64 + i * 16 + g * 4;
    #pragma unroll
    for (int j = 0; j < 2; ++j) {
      const int gcol = col0 + wc * 32 + j * 16 + m;
      #pragma unroll
      for (int e = 0; e < 4; ++e) {
        float gate = a2[i][j][e];
        float val = a1[i][j][e] * (gate / (1.f + expf(-gate)));
        if (to_v) v[(size_t)(grow + e) * 1024 + gcol] = val;
        else ffn[(size_t)(grow + e) * 2048 + (gcol - 1024)] = __float2bfloat16(val);
      }
    }
  }
}

// ---------------------------------------------------------------------------
// Final GEMM, BK=64: out = [ln16 (4096x1024) | ffn16 (4096x2048)] @ Wo_t^T
// ---------------------------------------------------------------------------
__global__ __launch_bounds__(256) void k_gemm_wo16(const __hip_bfloat16* __restrict__ A1,
                                                   const __hip_bfloat16* __restrict__ A2,
                                                   const __hip_bfloat16* __restrict__ Bt,
                                                   float* __restrict__ C) {
  const int Kt = 3072;
  __shared__ __align__(16) __hip_bfloat16 Al[128 * 64];
  __shared__ __align__(16) __hip_bfloat16 Bl[64 * 64];
  const int tid = threadIdx.x;
  const int wid = tid >> 6, lane = tid & 63;
  const int wr = wid >> 1, wc = wid & 1;
  const int row0 = blockIdx.y * 128, col0 = blockIdx.x * 64;
  const char* gsrc[6];
  char* ldst[6];
  #pragma unroll
  for (int i = 0; i < 6; ++i) {
    const int s = wid + i * 4;            // 0..23
    if (s < 16) {
      const int r = s * 8 + (lane >> 3);
      gsrc[i] = (const char*)(A1 + (size_t)(row0 + r) * 1024) + (lane & 7) * 16;
      ldst[i] = (char*)&Al[0] + s * 1024;
    } else {
      const int r = col0 + (s - 16) * 8 + (lane >> 3);
      gsrc[i] = (const char*)(Bt + (size_t)r * Kt) + (lane & 7) * 16;
      ldst[i] = (char*)&Bl[0] + (s - 16) * 1024;
    }
  }
  f32x4 acc[4][2];
  #pragma unroll
  for (int i = 0; i < 4; ++i)
    #pragma unroll
    for (int j = 0; j < 2; ++j)
      acc[i][j] = (f32x4){0.f, 0.f, 0.f, 0.f};
  const int g = lane >> 4, m = lane & 15;

  #define WO_STEP() do {                                                          \
    _Pragma("unroll")                                                             \
    for (int i = 0; i < 6; ++i) GLD(ldst[i], gsrc[i]);                            \
    _Pragma("unroll")                                                             \
    for (int i = 0; i < 6; ++i) gsrc[i] += 128;                                   \
    __syncthreads();                                                              \
    _Pragma("unroll")                                                             \
    for (int h = 0; h < 2; ++h) {                                                 \
      bf16x8 af[4], bfr[2];                                                       \
      _Pragma("unroll")                                                           \
      for (int i = 0; i < 4; ++i)                                                 \
        af[i] = *(const bf16x8*)&Al[(wr * 64 + i * 16 + m) * 64 + h * 32 + g * 8];\
      _Pragma("unroll")                                                           \
      for (int j = 0; j < 2; ++j)                                                 \
        bfr[j] = *(const bf16x8*)&Bl[(wc * 32 + j * 16 + m) * 64 + h * 32 + g * 8];\
      _Pragma("unroll")                                                           \
      for (int i = 0; i < 4; ++i)                                                 \
        _Pragma("unroll")                                                         \
        for (int j = 0; j < 2; ++j)                                               \
          acc[i][j] = __builtin_amdgcn_mfma_f32_16x16x32_bf16(af[i], bfr[j],      \
                                                              acc[i][j], 0, 0, 0);\
    }                                                                             \
    __syncthreads();                                                              \
  } while (0)

  for (int k0 = 0; k0 < 1024; k0 += 64) WO_STEP();
  // switch A source to ffn (stride 2048)
  #pragma unroll
  for (int i = 0; i < 6; ++i) {
    const int s = wid + i * 4;
    if (s < 16) {
      const int r = s * 8 + (lane >> 3);
      gsrc[i] = (const char*)(A2 + (size_t)(row0 + r) * 2048) + (lane & 7) * 16;
    }
  }
  for (int k0 = 0; k0 < 2048; k0 += 64) WO_STEP();
  #undef WO_STEP

  #pragma unroll
  for (int i = 0; i < 4; ++i) {
    const int grow = row0 + wr * 64 + i * 16 + g * 4;
    #pragma unroll
    for (int j = 0; j < 2; ++j) {
      const int gcol = col0 + wc * 32 + j * 16 + m;
      #pragma unroll
      for (int e = 0; e < 4; ++e)
        C[(size_t)(grow + e) * 1024 + gcol] = acc[i][j][e];
    }
  }
}

// ---------------------------------------------------------------------------
// WKV6 phase 1: per-chunk local recurrence from S=0 (batched reductions).
// ---------------------------------------------------------------------------
#define TTn 8
__global__ __launch_bounds__(256) void k_wkv1(const float* __restrict__ r,
                                              const float* __restrict__ e,
                                              const float* __restrict__ v,
                                              const float* __restrict__ u,
                                              float* __restrict__ o,
                                              float* __restrict__ Rd,
                                              float* __restrict__ Dtot,
                                              float* __restrict__ Inc) {
  int blk = blockIdx.x;
  int c = blk & (NCn - 1);
  int bh = blk >> 4;
  int b = bh >> 4, h = bh & 15;
  int tid = threadIdx.x, wave = tid >> 6, lane = tid & 63;
  size_t base = (size_t)b * Tn * Cn + (size_t)h * 64 + (size_t)c * Ln * Cn;
  int jbase = wave * 16 + (lane & 15);
  const int wu = __builtin_amdgcn_readfirstlane(wave);
  const size_t ubase = base + (size_t)wu * 16;
  float uv = u[h * 64 + jbase];
  float st[16];
  #pragma unroll
  for (int i = 0; i < 16; ++i) st[i] = 0.f;
  float cum = 1.f;
  __shared__ float yp[4][TTn][64];
  for (int tb = 0; tb < Ln / TTn; ++tb) {
    float rv8[TTn], ev8[TTn], vv8[TTn];
    #pragma unroll
    for (int tt = 0; tt < TTn; ++tt) {
      size_t off = base + (size_t)(tb * TTn + tt) * Cn;
      rv8[tt] = r[off + jbase];
      ev8[tt] = e[off + jbase];
      vv8[tt] = v[off + lane];
    }
    float yb[TTn];
    #pragma unroll
    for (int tt = 0; tt < TTn; ++tt) {
      const float rv = rv8[tt], ev = ev8[tt], vv = vv8[tt];
      if (lane < 16)
        Rd[base + (size_t)(tb * TTn + tt) * Cn + jbase] = rv * cum;
      cum *= ev;
      float p = rv * uv * (1.f - ev);
      p += __shfl_xor(p, 1, 16);
      p += __shfl_xor(p, 2, 16);
      p += __shfl_xor(p, 4, 16);
      p += __shfl_xor(p, 8, 16);
      float y = p * vv;
      const float* rrow = r + ubase + (size_t)(tb * TTn + tt) * Cn;
      const float* erow = e + ubase + (size_t)(tb * TTn + tt) * Cn;
      #pragma unroll
      for (int jj = 0; jj < 16; ++jj) {
        const float rj = rrow[jj];
        const float ej = erow[jj];
        const float kv = fmaf(-ej, vv, vv);   // (1-ej)*vv
        y = fmaf(rj, st[jj], y);
        st[jj] = fmaf(st[jj], ej, kv);
      }
      yb[tt] = y;
    }
    #pragma unroll
    for (int tt = 0; tt < TTn; ++tt) yp[wave][tt][lane] = yb[tt];
    __syncthreads();
    #pragma unroll
    for (int q = 0; q < TTn / 4; ++q) {
      int tt = wave * (TTn / 4) + q;
      size_t off = base + (size_t)(tb * TTn + tt) * Cn;
      o[off + lane] = yp[0][tt][lane] + yp[1][tt][lane] + yp[2][tt][lane] + yp[3][tt][lane];
    }
    __syncthreads();
  }
  size_t sbase = ((size_t)bh * NCn + c) * 4096;
  #pragma unroll
  for (int jj = 0; jj < 16; ++jj)
    Inc[sbase + (size_t)(wave * 16 + jj) * 64 + lane] = st[jj];
  if (lane < 16)
    Dtot[((size_t)bh * NCn + c) * 64 + jbase] = cum;
}

// ---------------------------------------------------------------------------
// WKV6 phase 2: sequential combine of chunk states, in place.
// ---------------------------------------------------------------------------
__global__ __launch_bounds__(256) void k_wkv2(float* __restrict__ S,
                                              const float* __restrict__ Dtot) {
  int bh = blockIdx.x;
  int tid = threadIdx.x;
  float4 s[4];
  #pragma unroll
  for (int j = 0; j < 4; ++j) { s[j].x = 0.f; s[j].y = 0.f; s[j].z = 0.f; s[j].w = 0.f; }
  size_t sb = (size_t)bh * NCn * 4096;
  for (int c = 0; c < NCn; ++c) {
    float4* entry = (float4*)(S + sb + (size_t)c * 4096);
    const float* dt = Dtot + ((size_t)bh * NCn + c) * 64;
    #pragma unroll
    for (int j = 0; j < 4; ++j) {
      int idx4 = tid + j * 256;
      int k = idx4 >> 4;
      float d = dt[k];
      float4 inc = entry[idx4];
      float4 cur = s[j];
      entry[idx4] = cur;
      s[j].x = fmaf(cur.x, d, inc.x);
      s[j].y = fmaf(cur.y, d, inc.y);
      s[j].z = fmaf(cur.z, d, inc.z);
      s[j].w = fmaf(cur.w, d, inc.w);
    }
  }
}

// ---------------------------------------------------------------------------
// WKV6 phase 3: o_t += rd_t . S_start_{chunk(t)}  (rd = r*Dcum, precomputed;
// per-lane vector load + v_readlane broadcast — proven fast form)
// ---------------------------------------------------------------------------
__global__ __launch_bounds__(256) void k_wkv3(const float* __restrict__ Rd,
                                              const float* __restrict__ S,
                                              float* __restrict__ o) {
  int blk = blockIdx.x;
  int c = blk & (NCn - 1);
  if (c == 0) return;
  int bh = blk >> 4;
  int b = bh >> 4, h = bh & 15;
  int tid = threadIdx.x, wave = tid >> 6, lane = tid & 63;
  const float* Sg = S + ((size_t)bh * NCn + c) * 4096;
  float sreg[64];
  #pragma unroll
  for (int k = 0; k < 64; ++k) sreg[k] = Sg[k * 64 + lane];
  size_t base = (size_t)b * Tn * Cn + (size_t)h * 64 + (size_t)c * Ln * Cn;
  for (int ti = 0; ti < 16; ++ti) {
    int t = wave * 16 + ti;
    size_t off = base + (size_t)t * Cn;
    float rd = Rd[off + lane];
    float y = 0.f;
    #pragma unroll
    for (int k = 0; k < 64; ++k)
      y = fmaf(rdlane(rd, k), sreg[k], y);
    o[off + lane] += y;
  }
}

// ---------------------------------------------------------------------------
// LayerNorm over C=1024 -> ln16 (bf16 4096x1024)
// ---------------------------------------------------------------------------
__global__ __launch_bounds__(256) void k_ln(const float* __restrict__ o,
                                            const float* __restrict__ g,
                                            const float* __restrict__ bta,
                                            __hip_bfloat16* __restrict__ ln16) {
  int bt = blockIdx.x, tid = threadIdx.x;
  const float4* row = (const float4*)(o + (size_t)bt * 1024);
  float4 v = row[tid];
  float s = v.x + v.y + v.z + v.w;
  float s2 = fmaf(v.x, v.x, fmaf(v.y, v.y, fmaf(v.z, v.z, v.w * v.w)));
  #pragma unroll
  for (int m = 1; m < 64; m <<= 1) {
    s += __shfl_xor(s, m, 64);
    s2 += __shfl_xor(s2, m, 64);
  }
  __shared__ float rs[4], rq[4];
  if ((tid & 63) == 0) { rs[tid >> 6] = s; rq[tid >> 6] = s2; }
  __syncthreads();
  s = rs[0] + rs[1] + rs[2] + rs[3];
  s2 = rq[0] + rq[1] + rq[2] + rq[3];
  float mu = s * (1.f / 1024.f);
  float var = s2 * (1.f / 1024.f) - mu * mu;
  float rstd = rsqrtf(var + 1e-5f);
  float4 gv = ((const float4*)g)[tid];
  float4 bv = ((const float4*)bta)[tid];
  ushort4 outv;
  outv.x = bfbits(fmaf((v.x - mu) * rstd, gv.x, bv.x));
  outv.y = bfbits(fmaf((v.y - mu) * rstd, gv.y, bv.y));
  outv.z = bfbits(fmaf((v.z - mu) * rstd, gv.z, bv.z));
  outv.w = bfbits(fmaf((v.w - mu) * rstd, gv.w, bv.w));
  ((ushort4*)((unsigned short*)ln16 + (size_t)bt * 1024))[tid] = outv;
}

// ---------------------------------------------------------------------------
extern "C" void kernel_launch(void* const* d_in, const int* in_sizes, int n_in,
                              void* d_out, int out_size, void* d_ws, size_t ws_size,
                              hipStream_t stream) {
  const float* x     = (const float*)d_in[0];
  const float* maa_x = (const float*)d_in[1];
  const float* maa_k = (const float*)d_in[2];
  const float* maa_v = (const float*)d_in[3];
  const float* maa_r = (const float*)d_in[4];
  const float* w1    = (const float*)d_in[5];
  const float* w2    = (const float*)d_in[6];
  const float* u     = (const float*)d_in[7];
  const float* Wr    = (const float*)d_in[8];
  const float* Wk    = (const float*)d_in[9];
  const float* Wvg   = (const float*)d_in[10];
  const float* Wo    = (const float*)d_in[11];
  const float* ln_g  = (const float*)d_in[12];
  const float* ln_b  = (const float*)d_in[13];
  float* out = (float*)d_out;
  float* ws = (float*)d_ws;

  // Workspace layout (floats), total 36M floats = 144 MB.
  const size_t M1 = 1048576;
  float* xx    = ws;                        //  0   .. 4M   f32  -> oo
  __hip_bfloat16* xxx16 = (__hip_bfloat16*)(ws + 4 * M1);  // 4M..6M (bf16) -> rr slot
  __hip_bfloat16* m1_16 = (__hip_bfloat16*)(ws + 8 * M1);  // 4096x96 bf16 -> Dtot
  __hip_bfloat16* w1t = (__hip_bfloat16*)(ws + 8 * M1 + 393216); // 96x1024 bf16
  __hip_bfloat16* w2t = (__hip_bfloat16*)(ws + 8 * M1 + 442368); // 3x1024x32 bf16
  __hip_bfloat16* xk16 = (__hip_bfloat16*)(ws + 8 * M1 + 524288);   // 8.5M..10.5M
  __hip_bfloat16* xv16 = (__hip_bfloat16*)(ws + 10 * M1 + 524288);  // 10.5M..12.5M
  __hip_bfloat16* xr16 = (__hip_bfloat16*)(ws + 12 * M1 + 524288);  // 12.5M..14.5M
  float* ee    = ws + 14 * M1 + 524288;     // 14.5M..18.5M f32
  float* vv    = ws + 18 * M1 + 524288;     // 18.5M..22.5M f32
  float* Sbuf  = ws + 22 * M1 + 524288;     // 22.5M..26.5M f32 Inc/S_start -> ln16
  __hip_bfloat16* ffn16 = (__hip_bfloat16*)(ws + 26 * M1 + 524288); // 26.5M..30.5M
  __hip_bfloat16* Wr16t = (__hip_bfloat16*)(ws + 30 * M1 + 524288); // 0.5M floats
  __hip_bfloat16* Wk16t = (__hip_bfloat16*)(ws + 31 * M1);          // 0.5M floats
  __hip_bfloat16* Wvg16t = (__hip_bfloat16*)(ws + 31 * M1 + 524288);// 3M floats
  __hip_bfloat16* Wo16t = (__hip_bfloat16*)(ws + 34 * M1 + 524288); // 1.5M floats
  float* rr = ws + 4 * M1;                  // overlays xxx16 (dead after mix1)
  float* oo = xx;
  float* Rd = ws + 8 * M1 + 524288;         // overlaps xk16/xv16 (dead by wkv1)
  float* Dtot = (float*)m1_16;              // m1 dead after mix2
  __hip_bfloat16* ln16 = (__hip_bfloat16*)Sbuf;  // after wkv3

  // weight converts + prep elementwise, one launch
  k_setup<<<15552, 256, 0, stream>>>(w1, w2, Wr, Wk, Wvg, Wo, x, maa_x,
                                     w1t, w2t, Wr16t, Wk16t, Wvg16t, Wo16t,
                                     xx, xxx16);
  // m1 = tanh(xxx @ w1) via MFMA (bf16 out)
  k_mix1_16<<<32, 256, 0, stream>>>(xxx16, w1t, m1_16);
  // fused m2 GEMM + token-mix epilogue -> xk/xv/xr bf16
  k_mix2_16<<<dim3(16, 32), 256, 0, stream>>>(m1_16, w2t, x, xx, maa_k, maa_v, maa_r,
                                              xk16, xv16, xr16);
  // merged: r = xr@Wr (z=0), e = exp(-exp(xk@Wk)) (z=1), BK=64
  k_gemm_re<<<dim3(16, 32, 2), 256, 0, stream>>>(xr16, Wr16t, rr, xk16, Wk16t, ee);
  // gated vg = xv @ Wvg -> v (f32) + ffn (bf16), 128x64 tiles, BK=64
  k_gemm_vg16<<<dim3(48, 32), 256, 0, stream>>>(xv16, Wvg16t, vv, ffn16);
  // WKV6 chunk-parallel scan
  k_wkv1<<<64 * NCn, 256, 0, stream>>>(rr, ee, vv, u, oo, Rd, Dtot, Sbuf);
  k_wkv2<<<64, 256, 0, stream>>>(Sbuf, Dtot);
  k_wkv3<<<64 * NCn, 256, 0, stream>>>(Rd, Sbuf, oo);
  // LayerNorm -> bf16 (Sbuf slot, S dead after wkv3)
  k_ln<<<4096, 256, 0, stream>>>(oo, ln_g, ln_b, ln16);
  // out = [ln16 | ffn16] @ Wo, BK=64
  k_gemm_wo16<<<dim3(16, 32), 256, 0, stream>>>(ln16, ffn16, Wo16t, out);
}

// Round 13
// 320.308 us; speedup vs baseline: 1.0377x; 1.0377x over previous
//
#include <hip/hip_runtime.h>
#include <hip/hip_bf16.h>
#include <math.h>

// Problem constants
#define Bn 4
#define Tn 1024
#define Cn 1024
#define Hn 16
#define Kn 64
#define DFn 2048
#define NCn 16      // WKV chunks
#define Ln 64       // chunk length (NCn*Ln == Tn)

typedef __bf16 bf16x8 __attribute__((ext_vector_type(8)));
typedef float f32x4 __attribute__((ext_vector_type(4)));

#define GLD(dst, src) \
  __builtin_amdgcn_global_load_lds((__attribute__((address_space(1))) const void*)(src), \
                                   (__attribute__((address_space(3))) void*)(dst), 16, 0, 0)

__device__ __forceinline__ float rdlane(float v, int l) {
  return __int_as_float(__builtin_amdgcn_readlane(__float_as_int(v), l));
}

__device__ __forceinline__ unsigned short bfbits(float f) {
  union { __hip_bfloat16 h; unsigned short u; } cv;
  cv.h = __float2bfloat16(f);
  return cv.u;
}

// ---------------------------------------------------------------------------
// Combined setup kernel: blocks [0, 11456) convert+transpose all weights to
// bf16 B^T layout; blocks [11456, 15552) do the prep elementwise pass.
// ---------------------------------------------------------------------------
__global__ __launch_bounds__(256) void k_setup(const float* __restrict__ w1,
                                               const float* __restrict__ w2,
                                               const float* __restrict__ Wr,
                                               const float* __restrict__ Wk,
                                               const float* __restrict__ Wvg,
                                               const float* __restrict__ Wo,
                                               const float* __restrict__ x,
                                               const float* __restrict__ maa_x,
                                               __hip_bfloat16* __restrict__ w1t,
                                               __hip_bfloat16* __restrict__ w2t,
                                               __hip_bfloat16* __restrict__ Wrt,
                                               __hip_bfloat16* __restrict__ Wkt,
                                               __hip_bfloat16* __restrict__ Wvgt,
                                               __hip_bfloat16* __restrict__ Wot,
                                               float* __restrict__ xx,
                                               __hip_bfloat16* __restrict__ xxx16) {
  int b = blockIdx.x;
  if (b >= 11456) {
    int idx = (b - 11456) * 256 + threadIdx.x;
    int c4 = idx & 255;
    int bt = idx >> 8;
    int t = bt & (Tn - 1);
    const float4* x4 = (const float4*)x;
    float4 xv = x4[idx];
    float4 xp;
    if (t > 0) xp = x4[idx - 256];
    else { xp.x = 0.f; xp.y = 0.f; xp.z = 0.f; xp.w = 0.f; }
    float4 d;
    d.x = xp.x - xv.x; d.y = xp.y - xv.y; d.z = xp.z - xv.z; d.w = xp.w - xv.w;
    float4 m = ((const float4*)maa_x)[c4];
    ushort4 o;
    o.x = bfbits(fmaf(d.x, m.x, xv.x));
    o.y = bfbits(fmaf(d.y, m.y, xv.y));
    o.z = bfbits(fmaf(d.z, m.z, xv.z));
    o.w = bfbits(fmaf(d.w, m.w, xv.w));
    ((float4*)xx)[idx] = d;
    ((ushort4*)xxx16)[idx] = o;
    return;
  }
  const float* W; __hip_bfloat16* Wt; int K, N, nx, rel;
  if (b < 96)        { W = w1;  Wt = w1t;  K = 1024; N = 96;   nx = 3;   rel = b; }
  else if (b < 192)  { int l = (b - 96) >> 5; rel = (b - 96) & 31;
                       W = w2 + l * 32768; Wt = w2t + l * 32768; K = 32; N = 1024; nx = 32; }
  else if (b < 1216) { W = Wr;  Wt = Wrt;  K = 1024; N = 1024; nx = 32;  rel = b - 192; }
  else if (b < 2240) { W = Wk;  Wt = Wkt;  K = 1024; N = 1024; nx = 32;  rel = b - 1216; }
  else if (b < 8384) { W = Wvg; Wt = Wvgt; K = 1024; N = 6144; nx = 192; rel = b - 2240; }
  else               { W = Wo;  Wt = Wot;  K = 3072; N = 1024; nx = 32;  rel = b - 8384; }
  int n0 = (rel % nx) * 32, k0 = (rel / nx) * 32;
  __shared__ float tile[32][33];
  int tid = threadIdx.x;
  int c = tid & 31, r = tid >> 5;   // r = 0..7
  #pragma unroll
  for (int i = 0; i < 4; ++i)
    tile[r + i * 8][c] = W[(size_t)(k0 + r + i * 8) * N + n0 + c];
  __syncthreads();
  #pragma unroll
  for (int i = 0; i < 4; ++i)
    Wt[(size_t)(n0 + r + i * 8) * K + k0 + c] = __float2bfloat16(tile[c][r + i * 8]);
}

// ---------------------------------------------------------------------------
// Kernel 2 (MFMA): m1 = tanh(xxx16 @ w1t^T)  -> bf16 (4096 x 96)
// ---------------------------------------------------------------------------
__global__ __launch_bounds__(256) void k_mix1_16(const __hip_bfloat16* __restrict__ A,
                                                 const __hip_bfloat16* __restrict__ Bt,
                                                 __hip_bfloat16* __restrict__ m1) {
  const int K = 1024;
  __shared__ __align__(16) __hip_bfloat16 Al[128 * 32];
  __shared__ __align__(16) __hip_bfloat16 Bl[96 * 32];
  const int tid = threadIdx.x;
  const int wid = tid >> 6, lane = tid & 63;
  const int wr = wid >> 1, wc = wid & 1;
  const int row0 = blockIdx.x * 128;
  const char* gsrc[4];
  char* ldst[4];
  bool act[4];
  #pragma unroll
  for (int i = 0; i < 4; ++i) {
    const int s = i * 4 + wid;
    act[i] = (s < 14);
    const int ss = act[i] ? s : 0;
    if (ss < 8) {
      const int r = ss * 16 + (lane >> 2);
      gsrc[i] = (const char*)(A + (size_t)(row0 + r) * K) + (lane & 3) * 16;
      ldst[i] = (char*)&Al[0] + ss * 1024;
    } else {
      const int r = (ss - 8) * 16 + (lane >> 2);
      gsrc[i] = (const char*)(Bt + (size_t)r * K) + (lane & 3) * 16;
      ldst[i] = (char*)&Bl[0] + (ss - 8) * 1024;
    }
  }
  f32x4 acc[4][3];
  #pragma unroll
  for (int i = 0; i < 4; ++i)
    #pragma unroll
    for (int j = 0; j < 3; ++j)
      acc[i][j] = (f32x4){0.f, 0.f, 0.f, 0.f};
  const int g = lane >> 4, m = lane & 15;
  for (int k0 = 0; k0 < K; k0 += 32) {
    #pragma unroll
    for (int i = 0; i < 4; ++i) if (act[i]) GLD(ldst[i], gsrc[i]);
    #pragma unroll
    for (int i = 0; i < 4; ++i) gsrc[i] += 64;
    __syncthreads();
    bf16x8 af[4], bfr[3];
    #pragma unroll
    for (int i = 0; i < 4; ++i)
      af[i] = *(const bf16x8*)&Al[(wr * 64 + i * 16 + m) * 32 + g * 8];
    #pragma unroll
    for (int j = 0; j < 3; ++j)
      bfr[j] = *(const bf16x8*)&Bl[(wc * 48 + j * 16 + m) * 32 + g * 8];
    #pragma unroll
    for (int i = 0; i < 4; ++i)
      #pragma unroll
      for (int j = 0; j < 3; ++j)
        acc[i][j] = __builtin_amdgcn_mfma_f32_16x16x32_bf16(af[i], bfr[j], acc[i][j], 0, 0, 0);
    __syncthreads();
  }
  #pragma unroll
  for (int i = 0; i < 4; ++i) {
    const int grow = row0 + wr * 64 + i * 16 + g * 4;
    #pragma unroll
    for (int j = 0; j < 3; ++j) {
      const int gcol = wc * 48 + j * 16 + m;
      #pragma unroll
      for (int e = 0; e < 4; ++e)
        m1[(size_t)(grow + e) * 96 + gcol] = __float2bfloat16(tanhf(acc[i][j][e]));
    }
  }
}

// ---------------------------------------------------------------------------
// Kernel 3 (MFMA, one-shot K): m_l = m1 @ w2t[l]^T (K=32 each), fused epilogue
// ---------------------------------------------------------------------------
__global__ __launch_bounds__(256) void k_mix2_16(const __hip_bfloat16* __restrict__ m1,
                                                 const __hip_bfloat16* __restrict__ w2t,
                                                 const float* __restrict__ x,
                                                 const float* __restrict__ xx,
                                                 const float* __restrict__ maa_k,
                                                 const float* __restrict__ maa_v,
                                                 const float* __restrict__ maa_r,
                                                 __hip_bfloat16* __restrict__ xk,
                                                 __hip_bfloat16* __restrict__ xv,
                                                 __hip_bfloat16* __restrict__ xr) {
  __shared__ __align__(16) __hip_bfloat16 Al[128 * 96];     // 24 KB contiguous
  __shared__ __align__(16) __hip_bfloat16 Bl[3 * 64 * 32];  // 12 KB
  const int tid = threadIdx.x;
  const int wid = tid >> 6, lane = tid & 63;
  const int wr = wid >> 1, wc = wid & 1;
  const int row0 = blockIdx.y * 128, col0 = blockIdx.x * 64;
  {
    const char* abase = (const char*)(m1 + (size_t)row0 * 96) + lane * 16;
    #pragma unroll
    for (int i = 0; i < 6; ++i) {
      const int s = wid + i * 4;          // 0..23
      GLD((char*)&Al[0] + s * 1024, abase + s * 1024);
    }
  }
  {
    const char* bbase = (const char*)w2t + (size_t)col0 * 64 + lane * 16;
    #pragma unroll
    for (int i = 0; i < 3; ++i) {
      const int s = wid + i * 4;          // 0..11
      const int l = s >> 2, q = s & 3;
      GLD((char*)&Bl[0] + s * 1024, bbase + (size_t)l * 65536 + q * 1024);
    }
  }
  __syncthreads();
  const int g = lane >> 4, m = lane & 15;
  f32x4 a0[4][2], a1[4][2], a2[4][2];
  #pragma unroll
  for (int i = 0; i < 4; ++i)
    #pragma unroll
    for (int j = 0; j < 2; ++j) {
      a0[i][j] = (f32x4){0.f,0.f,0.f,0.f};
      a1[i][j] = (f32x4){0.f,0.f,0.f,0.f};
      a2[i][j] = (f32x4){0.f,0.f,0.f,0.f};
    }
  #pragma unroll
  for (int l = 0; l < 3; ++l) {
    bf16x8 af[4], bfj[2];
    #pragma unroll
    for (int i = 0; i < 4; ++i)
      af[i] = *(const bf16x8*)&Al[(wr * 64 + i * 16 + m) * 96 + l * 32 + g * 8];
    #pragma unroll
    for (int j = 0; j < 2; ++j)
      bfj[j] = *(const bf16x8*)&Bl[(l * 64 + wc * 32 + j * 16 + m) * 32 + g * 8];
    #pragma unroll
    for (int i = 0; i < 4; ++i)
      #pragma unroll
      for (int j = 0; j < 2; ++j) {
        if (l == 0) a0[i][j] = __builtin_amdgcn_mfma_f32_16x16x32_bf16(af[i], bfj[j], a0[i][j], 0, 0, 0);
        if (l == 1) a1[i][j] = __builtin_amdgcn_mfma_f32_16x16x32_bf16(af[i], bfj[j], a1[i][j], 0, 0, 0);
        if (l == 2) a2[i][j] = __builtin_amdgcn_mfma_f32_16x16x32_bf16(af[i], bfj[j], a2[i][j], 0, 0, 0);
      }
  }
  #pragma unroll
  for (int i = 0; i < 4; ++i) {
    const int grow = row0 + wr * 64 + i * 16 + g * 4;
    #pragma unroll
    for (int j = 0; j < 2; ++j) {
      const int gcol = col0 + wc * 32 + j * 16 + m;
      const float mk_ = maa_k[gcol], mv_ = maa_v[gcol], mr_ = maa_r[gcol];
      #pragma unroll
      for (int e = 0; e < 4; ++e) {
        const size_t off = (size_t)(grow + e) * 1024 + gcol;
        const float xval = x[off], xxv = xx[off];
        xk[off] = __float2bfloat16(fmaf(xxv, mk_ + a0[i][j][e], xval));
        xv[off] = __float2bfloat16(fmaf(xxv, mv_ + a1[i][j][e], xval));
        xr[off] = __float2bfloat16(fmaf(xxv, mr_ + a2[i][j][e], xval));
      }
    }
  }
}

// ---------------------------------------------------------------------------
// Merged r/e GEMM: z=0: rr = xr @ Wr ; z=1: ee = exp(-exp(xk @ Wk))
// ---------------------------------------------------------------------------
__global__ __launch_bounds__(256) void k_gemm_re(const __hip_bfloat16* __restrict__ Ar,
                                                 const __hip_bfloat16* __restrict__ Btr,
                                                 float* __restrict__ Cr,
                                                 const __hip_bfloat16* __restrict__ Ak,
                                                 const __hip_bfloat16* __restrict__ Btk,
                                                 float* __restrict__ Ck) {
  const int K = 1024, N = 1024;
  const int z = blockIdx.z;
  const __hip_bfloat16* A  = z ? Ak : Ar;
  const __hip_bfloat16* Bt = z ? Btk : Btr;
  float* C = z ? Ck : Cr;
  __shared__ __align__(16) __hip_bfloat16 Al[128 * 32];
  __shared__ __align__(16) __hip_bfloat16 Bl[64 * 32];
  const int tid = threadIdx.x;
  const int wid = tid >> 6, lane = tid & 63;
  const int wr = wid >> 1, wc = wid & 1;
  const int row0 = blockIdx.y * 128, col0 = blockIdx.x * 64;
  const char* gsrc[3];
  char* ldst[3];
  #pragma unroll
  for (int i = 0; i < 3; ++i) {
    const int s = wid + i * 4;
    if (s < 8) {
      const int r = s * 16 + (lane >> 2);
      gsrc[i] = (const char*)(A + (size_t)(row0 + r) * K) + (lane & 3) * 16;
      ldst[i] = (char*)&Al[0] + s * 1024;
    } else {
      const int r = (s - 8) * 16 + (lane >> 2);
      gsrc[i] = (const char*)(Bt + (size_t)(col0 + r) * K) + (lane & 3) * 16;
      ldst[i] = (char*)&Bl[0] + (s - 8) * 1024;
    }
  }
  f32x4 acc[4][2];
  #pragma unroll
  for (int i = 0; i < 4; ++i)
    #pragma unroll
    for (int j = 0; j < 2; ++j)
      acc[i][j] = (f32x4){0.f, 0.f, 0.f, 0.f};
  const int g = lane >> 4, m = lane & 15;
  for (int k0 = 0; k0 < K; k0 += 32) {
    #pragma unroll
    for (int i = 0; i < 3; ++i) GLD(ldst[i], gsrc[i]);
    #pragma unroll
    for (int i = 0; i < 3; ++i) gsrc[i] += 64;
    __syncthreads();
    bf16x8 af[4], bfr[2];
    #pragma unroll
    for (int i = 0; i < 4; ++i)
      af[i] = *(const bf16x8*)&Al[(wr * 64 + i * 16 + m) * 32 + g * 8];
    #pragma unroll
    for (int j = 0; j < 2; ++j)
      bfr[j] = *(const bf16x8*)&Bl[(wc * 32 + j * 16 + m) * 32 + g * 8];
    #pragma unroll
    for (int i = 0; i < 4; ++i)
      #pragma unroll
      for (int j = 0; j < 2; ++j)
        acc[i][j] = __builtin_amdgcn_mfma_f32_16x16x32_bf16(af[i], bfr[j], acc[i][j], 0, 0, 0);
    __syncthreads();
  }
  #pragma unroll
  for (int i = 0; i < 4; ++i) {
    const int grow = row0 + wr * 64 + i * 16 + g * 4;
    #pragma unroll
    for (int j = 0; j < 2; ++j) {
      const int gcol = col0 + wc * 32 + j * 16 + m;
      #pragma unroll
      for (int e = 0; e < 4; ++e) {
        float val = acc[i][j][e];
        if (z) val = expf(-expf(val));
        C[(size_t)(grow + e) * N + gcol] = val;
      }
    }
  }
}

// ---------------------------------------------------------------------------
// Fused Wvg GEMM (128x64 tile — proven config)
// ---------------------------------------------------------------------------
__global__ __launch_bounds__(256) void k_gemm_vg16(const __hip_bfloat16* __restrict__ A,
                                                   const __hip_bfloat16* __restrict__ Bt,
                                                   float* __restrict__ v,
                                                   __hip_bfloat16* __restrict__ ffn) {
  const int K = 1024;
  __shared__ __align__(16) __hip_bfloat16 Al[128 * 32];
  __shared__ __align__(16) __hip_bfloat16 B1l[64 * 32];
  __shared__ __align__(16) __hip_bfloat16 B2l[64 * 32];
  const int tid = threadIdx.x;
  const int wid = tid >> 6, lane = tid & 63;
  const int wr = wid >> 1, wc = wid & 1;
  const int row0 = blockIdx.y * 128, col0 = blockIdx.x * 64;
  const char* gsrc[4];
  char* ldst[4];
  #pragma unroll
  for (int i = 0; i < 4; ++i) {
    const int s = wid + i * 4;
    if (s < 8) {
      const int r = s * 16 + (lane >> 2);
      gsrc[i] = (const char*)(A + (size_t)(row0 + r) * K) + (lane & 3) * 16;
      ldst[i] = (char*)&Al[0] + s * 1024;
    } else if (s < 12) {
      const int r = col0 + (s - 8) * 16 + (lane >> 2);
      gsrc[i] = (const char*)(Bt + (size_t)r * K) + (lane & 3) * 16;
      ldst[i] = (char*)&B1l[0] + (s - 8) * 1024;
    } else {
      const int r = 3072 + col0 + (s - 12) * 16 + (lane >> 2);
      gsrc[i] = (const char*)(Bt + (size_t)r * K) + (lane & 3) * 16;
      ldst[i] = (char*)&B2l[0] + (s - 12) * 1024;
    }
  }
  f32x4 a1[4][2], a2[4][2];
  #pragma unroll
  for (int i = 0; i < 4; ++i)
    #pragma unroll
    for (int j = 0; j < 2; ++j) {
      a1[i][j] = (f32x4){0.f, 0.f, 0.f, 0.f};
      a2[i][j] = (f32x4){0.f, 0.f, 0.f, 0.f};
    }
  const int g = lane >> 4, m = lane & 15;
  for (int k0 = 0; k0 < K; k0 += 32) {
    #pragma unroll
    for (int i = 0; i < 4; ++i) GLD(ldst[i], gsrc[i]);
    #pragma unroll
    for (int i = 0; i < 4; ++i) gsrc[i] += 64;
    __syncthreads();
    bf16x8 af[4], b1f[2], b2f[2];
    #pragma unroll
    for (int i = 0; i < 4; ++i)
      af[i] = *(const bf16x8*)&Al[(wr * 64 + i * 16 + m) * 32 + g * 8];
    #pragma unroll
    for (int j = 0; j < 2; ++j) {
      b1f[j] = *(const bf16x8*)&B1l[(wc * 32 + j * 16 + m) * 32 + g * 8];
      b2f[j] = *(const bf16x8*)&B2l[(wc * 32 + j * 16 + m) * 32 + g * 8];
    }
    #pragma unroll
    for (int i = 0; i < 4; ++i)
      #pragma unroll
      for (int j = 0; j < 2; ++j) {
        a1[i][j] = __builtin_amdgcn_mfma_f32_16x16x32_bf16(af[i], b1f[j], a1[i][j], 0, 0, 0);
        a2[i][j] = __builtin_amdgcn_mfma_f32_16x16x32_bf16(af[i], b2f[j], a2[i][j], 0, 0, 0);
      }
    __syncthreads();
  }
  const bool to_v = (col0 < 1024);
  #pragma unroll
  for (int i = 0; i < 4; ++i) {
    const int grow = row0 + wr * 64 + i * 16 + g * 4;
    #pragma unroll
    for (int j = 0; j < 2; ++j) {
      const int gcol = col0 + wc * 32 + j * 16 + m;
      #pragma unroll
      for (int e = 0; e < 4; ++e) {
        float gate = a2[i][j][e];
        float val = a1[i][j][e] * (gate / (1.f + expf(-gate)));
        if (to_v) v[(size_t)(grow + e) * 1024 + gcol] = val;
        else ffn[(size_t)(grow + e) * 2048 + (gcol - 1024)] = __float2bfloat16(val);
      }
    }
  }
}

// ---------------------------------------------------------------------------
// Final GEMM: out = [ln16 (4096x1024) | ffn16 (4096x2048)] @ Wo_t^T
// ---------------------------------------------------------------------------
__global__ __launch_bounds__(256) void k_gemm_wo16(const __hip_bfloat16* __restrict__ A1,
                                                   const __hip_bfloat16* __restrict__ A2,
                                                   const __hip_bfloat16* __restrict__ Bt,
                                                   float* __restrict__ C) {
  const int Kt = 3072;
  __shared__ __align__(16) __hip_bfloat16 Al[128 * 32];
  __shared__ __align__(16) __hip_bfloat16 Bl[64 * 32];
  const int tid = threadIdx.x;
  const int wid = tid >> 6, lane = tid & 63;
  const int wr = wid >> 1, wc = wid & 1;
  const int row0 = blockIdx.y * 128, col0 = blockIdx.x * 64;
  const char* gsrc[3];
  char* ldst[3];
  #pragma unroll
  for (int i = 0; i < 3; ++i) {
    const int s = wid + i * 4;
    if (s < 8) {
      const int r = s * 16 + (lane >> 2);
      gsrc[i] = (const char*)(A1 + (size_t)(row0 + r) * 1024) + (lane & 3) * 16;
      ldst[i] = (char*)&Al[0] + s * 1024;
    } else {
      const int r = col0 + (s - 8) * 16 + (lane >> 2);
      gsrc[i] = (const char*)(Bt + (size_t)r * Kt) + (lane & 3) * 16;
      ldst[i] = (char*)&Bl[0] + (s - 8) * 1024;
    }
  }
  f32x4 acc[4][2];
  #pragma unroll
  for (int i = 0; i < 4; ++i)
    #pragma unroll
    for (int j = 0; j < 2; ++j)
      acc[i][j] = (f32x4){0.f, 0.f, 0.f, 0.f};
  const int g = lane >> 4, m = lane & 15;

  #define WO_STEP() do {                                                          \
    _Pragma("unroll")                                                             \
    for (int i = 0; i < 3; ++i) GLD(ldst[i], gsrc[i]);                            \
    _Pragma("unroll")                                                             \
    for (int i = 0; i < 3; ++i) gsrc[i] += 64;                                    \
    __syncthreads();                                                              \
    bf16x8 af[4], bfr[2];                                                         \
    _Pragma("unroll")                                                             \
    for (int i = 0; i < 4; ++i)                                                   \
      af[i] = *(const bf16x8*)&Al[(wr * 64 + i * 16 + m) * 32 + g * 8];           \
    _Pragma("unroll")                                                             \
    for (int j = 0; j < 2; ++j)                                                   \
      bfr[j] = *(const bf16x8*)&Bl[(wc * 32 + j * 16 + m) * 32 + g * 8];          \
    _Pragma("unroll")                                                             \
    for (int i = 0; i < 4; ++i)                                                   \
      _Pragma("unroll")                                                           \
      for (int j = 0; j < 2; ++j)                                                 \
        acc[i][j] = __builtin_amdgcn_mfma_f32_16x16x32_bf16(af[i], bfr[j],        \
                                                            acc[i][j], 0, 0, 0); \
    __syncthreads();                                                              \
  } while (0)

  for (int k0 = 0; k0 < 1024; k0 += 32) WO_STEP();
  #pragma unroll
  for (int i = 0; i < 3; ++i) {
    const int s = wid + i * 4;
    if (s < 8) {
      const int r = s * 16 + (lane >> 2);
      gsrc[i] = (const char*)(A2 + (size_t)(row0 + r) * 2048) + (lane & 3) * 16;
    }
  }
  for (int k0 = 0; k0 < 2048; k0 += 32) WO_STEP();
  #undef WO_STEP

  #pragma unroll
  for (int i = 0; i < 4; ++i) {
    const int grow = row0 + wr * 64 + i * 16 + g * 4;
    #pragma unroll
    for (int j = 0; j < 2; ++j) {
      const int gcol = col0 + wc * 32 + j * 16 + m;
      #pragma unroll
      for (int e = 0; e < 4; ++e)
        C[(size_t)(grow + e) * 1024 + gcol] = acc[i][j][e];
    }
  }
}

// ---------------------------------------------------------------------------
// WKV6 phase 1: per-chunk local recurrence from S=0 (batched reductions).
// Scalar broadcast loads for r/e rows (hidden under VALU body); stores
// rd = r * Dcum for wkv3.
// ---------------------------------------------------------------------------
#define TTn 8
__global__ __launch_bounds__(256) void k_wkv1(const float* __restrict__ r,
                                              const float* __restrict__ e,
                                              const float* __restrict__ v,
                                              const float* __restrict__ u,
                                              float* __restrict__ o,
                                              float* __restrict__ Rd,
                                              float* __restrict__ Dtot,
                                              float* __restrict__ Inc) {
  int blk = blockIdx.x;
  int c = blk & (NCn - 1);
  int bh = blk >> 4;
  int b = bh >> 4, h = bh & 15;
  int tid = threadIdx.x, wave = tid >> 6, lane = tid & 63;
  size_t base = (size_t)b * Tn * Cn + (size_t)h * 64 + (size_t)c * Ln * Cn;
  int jbase = wave * 16 + (lane & 15);
  const int wu = __builtin_amdgcn_readfirstlane(wave);
  const size_t ubase = base + (size_t)wu * 16;
  float uv = u[h * 64 + jbase];
  float st[16];
  #pragma unroll
  for (int i = 0; i < 16; ++i) st[i] = 0.f;
  float cum = 1.f;
  __shared__ float yp[4][TTn][64];
  for (int tb = 0; tb < Ln / TTn; ++tb) {
    float rv8[TTn], ev8[TTn], vv8[TTn];
    #pragma unroll
    for (int tt = 0; tt < TTn; ++tt) {
      size_t off = base + (size_t)(tb * TTn + tt) * Cn;
      rv8[tt] = r[off + jbase];
      ev8[tt] = e[off + jbase];
      vv8[tt] = v[off + lane];
    }
    float yb[TTn];
    #pragma unroll
    for (int tt = 0; tt < TTn; ++tt) {
      const float rv = rv8[tt], ev = ev8[tt], vv = vv8[tt];
      if (lane < 16)
        Rd[base + (size_t)(tb * TTn + tt) * Cn + jbase] = rv * cum;
      cum *= ev;
      float p = rv * uv * (1.f - ev);
      p += __shfl_xor(p, 1, 16);
      p += __shfl_xor(p, 2, 16);
      p += __shfl_xor(p, 4, 16);
      p += __shfl_xor(p, 8, 16);
      float y = p * vv;
      const float* rrow = r + ubase + (size_t)(tb * TTn + tt) * Cn;
      const float* erow = e + ubase + (size_t)(tb * TTn + tt) * Cn;
      #pragma unroll
      for (int jj = 0; jj < 16; ++jj) {
        const float rj = rrow[jj];
        const float ej = erow[jj];
        const float kv = fmaf(-ej, vv, vv);   // (1-ej)*vv
        y = fmaf(rj, st[jj], y);
        st[jj] = fmaf(st[jj], ej, kv);
      }
      yb[tt] = y;
    }
    #pragma unroll
    for (int tt = 0; tt < TTn; ++tt) yp[wave][tt][lane] = yb[tt];
    __syncthreads();
    #pragma unroll
    for (int q = 0; q < TTn / 4; ++q) {
      int tt = wave * (TTn / 4) + q;
      size_t off = base + (size_t)(tb * TTn + tt) * Cn;
      o[off + lane] = yp[0][tt][lane] + yp[1][tt][lane] + yp[2][tt][lane] + yp[3][tt][lane];
    }
    __syncthreads();
  }
  size_t sbase = ((size_t)bh * NCn + c) * 4096;
  #pragma unroll
  for (int jj = 0; jj < 16; ++jj)
    Inc[sbase + (size_t)(wave * 16 + jj) * 64 + lane] = st[jj];
  if (lane < 16)
    Dtot[((size_t)bh * NCn + c) * 64 + jbase] = cum;
}

// ---------------------------------------------------------------------------
// WKV6 phase 2: sequential combine of chunk states, in place.
// ---------------------------------------------------------------------------
__global__ __launch_bounds__(256) void k_wkv2(float* __restrict__ S,
                                              const float* __restrict__ Dtot) {
  int bh = blockIdx.x;
  int tid = threadIdx.x;
  float4 s[4];
  #pragma unroll
  for (int j = 0; j < 4; ++j) { s[j].x = 0.f; s[j].y = 0.f; s[j].z = 0.f; s[j].w = 0.f; }
  size_t sb = (size_t)bh * NCn * 4096;
  for (int c = 0; c < NCn; ++c) {
    float4* entry = (float4*)(S + sb + (size_t)c * 4096);
    const float* dt = Dtot + ((size_t)bh * NCn + c) * 64;
    #pragma unroll
    for (int j = 0; j < 4; ++j) {
      int idx4 = tid + j * 256;
      int k = idx4 >> 4;
      float d = dt[k];
      float4 inc = entry[idx4];
      float4 cur = s[j];
      entry[idx4] = cur;
      s[j].x = fmaf(cur.x, d, inc.x);
      s[j].y = fmaf(cur.y, d, inc.y);
      s[j].z = fmaf(cur.z, d, inc.z);
      s[j].w = fmaf(cur.w, d, inc.w);
    }
  }
}

// ---------------------------------------------------------------------------
// WKV6 phase 3: o_t += rd_t . S_start_{chunk(t)}  (rd = r*Dcum, precomputed;
// per-lane vector load + v_readlane broadcast — proven fast form)
// ---------------------------------------------------------------------------
__global__ __launch_bounds__(256) void k_wkv3(const float* __restrict__ Rd,
                                              const float* __restrict__ S,
                                              float* __restrict__ o) {
  int blk = blockIdx.x;
  int c = blk & (NCn - 1);
  if (c == 0) return;
  int bh = blk >> 4;
  int b = bh >> 4, h = bh & 15;
  int tid = threadIdx.x, wave = tid >> 6, lane = tid & 63;
  const float* Sg = S + ((size_t)bh * NCn + c) * 4096;
  float sreg[64];
  #pragma unroll
  for (int k = 0; k < 64; ++k) sreg[k] = Sg[k * 64 + lane];
  size_t base = (size_t)b * Tn * Cn + (size_t)h * 64 + (size_t)c * Ln * Cn;
  for (int ti = 0; ti < 16; ++ti) {
    int t = wave * 16 + ti;
    size_t off = base + (size_t)t * Cn;
    float rd = Rd[off + lane];
    float y = 0.f;
    #pragma unroll
    for (int k = 0; k < 64; ++k)
      y = fmaf(rdlane(rd, k), sreg[k], y);
    o[off + lane] += y;
  }
}

// ---------------------------------------------------------------------------
// LayerNorm over C=1024 -> ln16 (bf16 4096x1024)
// ---------------------------------------------------------------------------
__global__ __launch_bounds__(256) void k_ln(const float* __restrict__ o,
                                            const float* __restrict__ g,
                                            const float* __restrict__ bta,
                                            __hip_bfloat16* __restrict__ ln16) {
  int bt = blockIdx.x, tid = threadIdx.x;
  const float4* row = (const float4*)(o + (size_t)bt * 1024);
  float4 v = row[tid];
  float s = v.x + v.y + v.z + v.w;
  float s2 = fmaf(v.x, v.x, fmaf(v.y, v.y, fmaf(v.z, v.z, v.w * v.w)));
  #pragma unroll
  for (int m = 1; m < 64; m <<= 1) {
    s += __shfl_xor(s, m, 64);
    s2 += __shfl_xor(s2, m, 64);
  }
  __shared__ float rs[4], rq[4];
  if ((tid & 63) == 0) { rs[tid >> 6] = s; rq[tid >> 6] = s2; }
  __syncthreads();
  s = rs[0] + rs[1] + rs[2] + rs[3];
  s2 = rq[0] + rq[1] + rq[2] + rq[3];
  float mu = s * (1.f / 1024.f);
  float var = s2 * (1.f / 1024.f) - mu * mu;
  float rstd = rsqrtf(var + 1e-5f);
  float4 gv = ((const float4*)g)[tid];
  float4 bv = ((const float4*)bta)[tid];
  ushort4 outv;
  outv.x = bfbits(fmaf((v.x - mu) * rstd, gv.x, bv.x));
  outv.y = bfbits(fmaf((v.y - mu) * rstd, gv.y, bv.y));
  outv.z = bfbits(fmaf((v.z - mu) * rstd, gv.z, bv.z));
  outv.w = bfbits(fmaf((v.w - mu) * rstd, gv.w, bv.w));
  ((ushort4*)((unsigned short*)ln16 + (size_t)bt * 1024))[tid] = outv;
}

// ---------------------------------------------------------------------------
extern "C" void kernel_launch(void* const* d_in, const int* in_sizes, int n_in,
                              void* d_out, int out_size, void* d_ws, size_t ws_size,
                              hipStream_t stream) {
  const float* x     = (const float*)d_in[0];
  const float* maa_x = (const float*)d_in[1];
  const float* maa_k = (const float*)d_in[2];
  const float* maa_v = (const float*)d_in[3];
  const float* maa_r = (const float*)d_in[4];
  const float* w1    = (const float*)d_in[5];
  const float* w2    = (const float*)d_in[6];
  const float* u     = (const float*)d_in[7];
  const float* Wr    = (const float*)d_in[8];
  const float* Wk    = (const float*)d_in[9];
  const float* Wvg   = (const float*)d_in[10];
  const float* Wo    = (const float*)d_in[11];
  const float* ln_g  = (const float*)d_in[12];
  const float* ln_b  = (const float*)d_in[13];
  float* out = (float*)d_out;
  float* ws = (float*)d_ws;

  // Workspace layout (floats), total 36M floats = 144 MB.
  const size_t M1 = 1048576;
  float* xx    = ws;                        //  0   .. 4M   f32  -> oo
  __hip_bfloat16* xxx16 = (__hip_bfloat16*)(ws + 4 * M1);  // 4M..6M (bf16) -> rr slot
  __hip_bfloat16* m1_16 = (__hip_bfloat16*)(ws + 8 * M1);  // 4096x96 bf16 -> Dtot
  __hip_bfloat16* w1t = (__hip_bfloat16*)(ws + 8 * M1 + 393216); // 96x1024 bf16
  __hip_bfloat16* w2t = (__hip_bfloat16*)(ws + 8 * M1 + 442368); // 3x1024x32 bf16
  __hip_bfloat16* xk16 = (__hip_bfloat16*)(ws + 8 * M1 + 524288);   // 8.5M..10.5M
  __hip_bfloat16* xv16 = (__hip_bfloat16*)(ws + 10 * M1 + 524288);  // 10.5M..12.5M
  __hip_bfloat16* xr16 = (__hip_bfloat16*)(ws + 12 * M1 + 524288);  // 12.5M..14.5M
  float* ee    = ws + 14 * M1 + 524288;     // 14.5M..18.5M f32
  float* vv    = ws + 18 * M1 + 524288;     // 18.5M..22.5M f32
  float* Sbuf  = ws + 22 * M1 + 524288;     // 22.5M..26.5M f32 Inc/S_start -> ln16
  __hip_bfloat16* ffn16 = (__hip_bfloat16*)(ws + 26 * M1 + 524288); // 26.5M..30.5M
  __hip_bfloat16* Wr16t = (__hip_bfloat16*)(ws + 30 * M1 + 524288); // 0.5M floats
  __hip_bfloat16* Wk16t = (__hip_bfloat16*)(ws + 31 * M1);          // 0.5M floats
  __hip_bfloat16* Wvg16t = (__hip_bfloat16*)(ws + 31 * M1 + 524288);// 3M floats
  __hip_bfloat16* Wo16t = (__hip_bfloat16*)(ws + 34 * M1 + 524288); // 1.5M floats
  float* rr = ws + 4 * M1;                  // overlays xxx16 (dead after mix1)
  float* oo = xx;
  float* Rd = ws + 8 * M1 + 524288;         // overlaps xk16/xv16 (dead by wkv1)
  float* Dtot = (float*)m1_16;              // m1 dead after mix2
  __hip_bfloat16* ln16 = (__hip_bfloat16*)Sbuf;  // after wkv3

  // weight converts + prep elementwise, one launch
  k_setup<<<15552, 256, 0, stream>>>(w1, w2, Wr, Wk, Wvg, Wo, x, maa_x,
                                     w1t, w2t, Wr16t, Wk16t, Wvg16t, Wo16t,
                                     xx, xxx16);
  // m1 = tanh(xxx @ w1) via MFMA (bf16 out)
  k_mix1_16<<<32, 256, 0, stream>>>(xxx16, w1t, m1_16);
  // fused m2 GEMM + token-mix epilogue -> xk/xv/xr bf16
  k_mix2_16<<<dim3(16, 32), 256, 0, stream>>>(m1_16, w2t, x, xx, maa_k, maa_v, maa_r,
                                              xk16, xv16, xr16);
  // merged: r = xr@Wr (z=0), e = exp(-exp(xk@Wk)) (z=1)
  k_gemm_re<<<dim3(16, 32, 2), 256, 0, stream>>>(xr16, Wr16t, rr, xk16, Wk16t, ee);
  // gated vg = xv @ Wvg -> v (f32) + ffn (bf16), 128x64 tiles (proven)
  k_gemm_vg16<<<dim3(48, 32), 256, 0, stream>>>(xv16, Wvg16t, vv, ffn16);
  // WKV6 chunk-parallel scan
  k_wkv1<<<64 * NCn, 256, 0, stream>>>(rr, ee, vv, u, oo, Rd, Dtot, Sbuf);
  k_wkv2<<<64, 256, 0, stream>>>(Sbuf, Dtot);
  k_wkv3<<<64 * NCn, 256, 0, stream>>>(Rd, Sbuf, oo);
  // LayerNorm -> bf16 (Sbuf slot, S dead after wkv3)
  k_ln<<<4096, 256, 0, stream>>>(oo, ln_g, ln_b, ln16);
  // out = [ln16 | ffn16] @ Wo
  k_gemm_wo16<<<dim3(16, 32), 256, 0, stream>>>(ln16, ffn16, Wo16t, out);
}